// Round 8
// baseline (81.553 us; speedup 1.0000x reference)
//
#include <hip/hip_runtime.h>
#include <math.h>

#define LSEQ 512
#define EDIM 256
#define PDIM 2048
#define BM   128
#define BK   32
#define NT   16      // K-steps = LSEQ/BK

typedef _Float16 f16x8  __attribute__((ext_vector_type(8)));
typedef _Float16 f16x2  __attribute__((ext_vector_type(2)));
typedef float    f32x16 __attribute__((ext_vector_type(16)));

#if __has_builtin(__builtin_amdgcn_exp2f)
#define EXP2F(x) __builtin_amdgcn_exp2f(x)
#else
#define EXP2F(x) __expf((x) * 0.6931471805599453f)
#endif

__device__ inline f16x2 pk2(float a, float b) {
#if __has_builtin(__builtin_amdgcn_cvt_pkrtz)
    return __builtin_bit_cast(f16x2, __builtin_amdgcn_cvt_pkrtz(a, b));
#else
    f16x2 r; r[0] = (_Float16)a; r[1] = (_Float16)b; return r;
#endif
}

__device__ inline float hw_sin(float ang) {
#if __has_builtin(__builtin_amdgcn_sinf)
    float rev = ang * 0.15915494309189535f;
    return __builtin_amdgcn_sinf(rev - floorf(rev));
#else
    return sinf(ang);
#endif
}
__device__ inline float hw_cos(float ang) {
#if __has_builtin(__builtin_amdgcn_cosf)
    float rev = ang * 0.15915494309189535f;
    return __builtin_amdgcn_cosf(rev - floorf(rev));
#else
    return cosf(ang);
#endif
}

// Conflict-balanced interleaved tile layout (fp16 element offset) for a
// [rows][32] fp16 tile stored as 128B row-pairs. r = row, g = k-group (0..3).
// Any 32-consecutive-row x fixed-g b128 access spreads 8 words/bank.
// Note: tile_off(r+32,g) = tile_off(r,g) + 1024, tile_off(r+64,g) = +2048.
__device__ __host__ inline int tile_off(int r, int g) {
    return ((r >> 1) << 6) + ((r & 1) << 5) + (((g ^ ((r >> 1) & 3)) & 3) << 3);
}

__device__ inline void g2lds16(const void* g, void* l) {
    __builtin_amdgcn_global_load_lds(
        (const __attribute__((address_space(1))) void*)g,
        (__attribute__((address_space(3))) void*)l, 16, 0, 0);
}

// ---- fused precompute: one block per (b, k-step) baset chunk ---------------
// Also writes params[b, l] = {-0.5/w^2 * log2e, log2(amp)} for its 32 l's.
__global__ __launch_bounds__(256) void precompute_all(
    const int*   __restrict__ bs,      // (B, L)
    const float* __restrict__ ls,      // (256, 3)
    const float* __restrict__ emb,     // (256, E)
    float2*      __restrict__ params,  // (B, L)
    _Float16*    __restrict__ baset) { // (B*NT) chunks of 16 KB
    const int b   = blockIdx.x >> 4;
    const int t   = blockIdx.x & 15;
    const int tid = threadIdx.x;       // = e (0..255)

    __shared__ int sByte[BK];
    if (tid < BK) {
        const int l    = t * BK + tid;
        const int byte = bs[b * LSEQ + l];
        sByte[tid] = byte;
        const float l1  = ls[byte * 3 + 1];
        const float l2  = ls[byte * 3 + 2];
        const float wdt = fabsf(l1) * 0.02f + 1e-5f;
        const float amp = 1.0f / (1.0f + __expf(-l2));
        params[b * LSEQ + l] = make_float2(-0.72134752f / (wdt * wdt),  // -0.5*log2e/w^2
                                           __log2f(amp));
    }
    __syncthreads();

    // PE dim e: pair index e>>1, phase e&1 (0=sin, 1=cos)
    const float div = __expf((float)(tid >> 1) * (-2.0f * 9.210340372f / 256.0f));
    _Float16* chunk = baset + ((size_t)blockIdx.x << 13);
#pragma unroll
    for (int g = 0; g < 4; ++g) {
        f16x8 v;
#pragma unroll
        for (int j = 0; j < 8; ++j) {
            const int lj  = g * 8 + j;
            const float ang = (float)(t * BK + lj) * div;
            const float pev = (tid & 1) ? hw_cos(ang) : hw_sin(ang);
            v[j] = (_Float16)(emb[sByte[lj] * EDIM + tid] + pev);
        }
        *(f16x8*)&chunk[tile_off(tid, g)] = v;
    }
}

// ----------------------------- MFMA field kernel ----------------------------
// 256 thr (4 waves, 2x2 grid). Block tile 128p x 256e, wave tile 64p x 128e.
// BK=32, 16 K-steps, 2-phase dbuf, 32x32x16 f16 MFMA, acc 2rt x 4ct x f32x16.
__global__ __launch_bounds__(256, 3) void field_mfma(
    const float*    __restrict__ cpos,    // (B,P)
    const float2*   __restrict__ params,  // (B,L) {c2*log2e, log2(amp)}
    const _Float16* __restrict__ baset,   // pre-swizzled BASE^T chunks
    float*          __restrict__ out) {   // (B,P,E)

    __shared__ __align__(16) _Float16 sW[2][BM * BK];    // 2 x 8 KB
    __shared__ __align__(16) _Float16 sB[2][EDIM * BK];  // 2 x 16 KB

    const int orig = blockIdx.x;
    const int wg   = (orig & 7) * 128 + (orig >> 3);     // bijective XCD swizzle
    const int b    = wg >> 4;
    const int pt   = wg & 15;

    const int tid = threadIdx.x, lane = tid & 63, wave = tid >> 6;
    const int l31 = lane & 31, h = lane >> 5;            // 32x32 frag lane map
    const int wrow = wave >> 1, wcol = wave & 1;         // 2 x 2 wave grid

    // W-gen role: thread -> (k-group kg, rows r0 and r0+64)
    const int kg = tid & 3;
    const int r0 = tid >> 2;                             // 0..63
    const float pos0 = cpos[b * PDIM + pt * BM + r0];
    const float pos1 = cpos[b * PDIM + pt * BM + r0 + 64];
    const float invL = 1.0f / (float)(LSEQ - 1);
    const int woff0 = tile_off(r0, kg);
    const int woff1 = woff0 + 2048;                      // rows +64

    // frag read offsets: A row = wrow*64 + rt*32 + l31 (rt via +1024),
    //                    B row = wcol*128 + ct*32 + l31 (ct via +1024*ct)
    int aoff[2], boff[2];
#pragma unroll
    for (int kk = 0; kk < 2; ++kk) {
        aoff[kk] = tile_off(wrow * 64 + l31, kk * 2 + h);
        boff[kk] = tile_off(wcol * 128 + l31, kk * 2 + h);
    }

    const float2* prm = params + b * LSEQ;
    const _Float16* bt = baset + ((size_t)b * NT << 13);

    // ---- prologue: stage B0,B1; params for t=0; genW(0) ----
#pragma unroll
    for (int buf = 0; buf < 2; ++buf) {
        const _Float16* src = bt + buf * 8192 + wave * 2048 + lane * 8;
#pragma unroll
        for (int i = 0; i < 4; ++i)
            g2lds16(src + i * 512, &sB[buf][wave * 2048 + i * 512 + lane * 8]);
    }

    float4 q0, q1, q2, q3;
    {
        const float4* qp = (const float4*)(prm + kg * 8);
        q0 = qp[0]; q1 = qp[1]; q2 = qp[2]; q3 = qp[3];
    }

    // genW for K-step t into sW[dbuf] using q0..q3 (params for this t)
    auto genW = [&](int t, int dbuf) {
        const float bl0 = (float)(t * BK + kg * 8) * invL;
        const float pd0 = pos0 - bl0;
        const float pd1 = pos1 - bl0;
        float wa[8], wb[8];
#define GW(i, c2, la) { float d0 = pd0 - (float)(i) * invL;            \
                        wa[i] = EXP2F(fmaf(d0 * d0, (c2), (la)));      \
                        float d1 = pd1 - (float)(i) * invL;            \
                        wb[i] = EXP2F(fmaf(d1 * d1, (c2), (la))); }
        GW(0, q0.x, q0.y) GW(1, q0.z, q0.w)
        GW(2, q1.x, q1.y) GW(3, q1.z, q1.w)
        GW(4, q2.x, q2.y) GW(5, q2.z, q2.w)
        GW(6, q3.x, q3.y) GW(7, q3.z, q3.w)
#undef GW
        f16x8 va, vb;
        ((f16x2*)&va)[0] = pk2(wa[0], wa[1]); ((f16x2*)&va)[1] = pk2(wa[2], wa[3]);
        ((f16x2*)&va)[2] = pk2(wa[4], wa[5]); ((f16x2*)&va)[3] = pk2(wa[6], wa[7]);
        ((f16x2*)&vb)[0] = pk2(wb[0], wb[1]); ((f16x2*)&vb)[1] = pk2(wb[2], wb[3]);
        ((f16x2*)&vb)[2] = pk2(wb[4], wb[5]); ((f16x2*)&vb)[3] = pk2(wb[6], wb[7]);
        *(f16x8*)&sW[dbuf][woff0] = va;
        *(f16x8*)&sW[dbuf][woff1] = vb;
    };

    genW(0, 0);
    __syncthreads();

    f32x16 acc[2][4];
#pragma unroll
    for (int i = 0; i < 2; ++i)
#pragma unroll
        for (int j = 0; j < 4; ++j) acc[i][j] = (f32x16)(0.f);

    // ---- main loop ----
    for (int t = 0; t < NT; ++t) {
        const int cur = t & 1;

        if (t < NT - 1) {   // prefetch params for t+1 (lands under MFMA)
            const float4* qp = (const float4*)(prm + (t + 1) * BK + kg * 8);
            q0 = qp[0]; q1 = qp[1]; q2 = qp[2]; q3 = qp[3];
        }

        const _Float16* wb_ = sW[cur];
        const _Float16* bb_ = sB[cur];
        __builtin_amdgcn_s_setprio(1);
#pragma unroll
        for (int kk = 0; kk < 2; ++kk) {
            f16x8 fa[2], fb[4];
#pragma unroll
            for (int rt = 0; rt < 2; ++rt)
                fa[rt] = *(const f16x8*)&wb_[aoff[kk] + rt * 1024];
#pragma unroll
            for (int ct = 0; ct < 4; ++ct)
                fb[ct] = *(const f16x8*)&bb_[boff[kk] + ct * 1024];
#pragma unroll
            for (int ct = 0; ct < 4; ++ct)
#pragma unroll
                for (int rt = 0; rt < 2; ++rt)
                    acc[rt][ct] = __builtin_amdgcn_mfma_f32_32x32x16_f16(fa[rt], fb[ct], acc[rt][ct], 0, 0, 0);
        }
        __builtin_amdgcn_s_setprio(0);

        if (t < NT - 1) genW(t + 1, cur ^ 1);  // after MFMA: no lgkm coupling

        __syncthreads();   // drains W[t+1] writes + B[t+1] stage gloads

        if (t < NT - 2) {  // issue B[t+2] into the buffer just freed
            const _Float16* src = bt + (t + 2) * 8192 + wave * 2048 + lane * 8;
#pragma unroll
            for (int i = 0; i < 4; ++i)
                g2lds16(src + i * 512, &sB[cur][wave * 2048 + i * 512 + lane * 8]);
        }
    }

    // ---- epilogue: C/D 32x32 layout col=lane&31, row=(reg&3)+8(reg>>2)+4h --
#pragma unroll
    for (int rt = 0; rt < 2; ++rt)
#pragma unroll
        for (int ct = 0; ct < 4; ++ct) {
            const int e = wcol * 128 + ct * 32 + l31;
            const int pbase = pt * BM + wrow * 64 + rt * 32 + 4 * h;
#pragma unroll
            for (int reg = 0; reg < 16; ++reg) {
                const int p = pbase + (reg & 3) + 8 * (reg >> 2);
                out[((size_t)b * PDIM + p) * EDIM + e] = acc[rt][ct][reg];
            }
        }
}

extern "C" void kernel_launch(void* const* d_in, const int* in_sizes, int n_in,
                              void* d_out, int out_size, void* d_ws, size_t ws_size,
                              hipStream_t stream) {
    const int*   bs   = (const int*)d_in[0];
    const float* cpos = (const float*)d_in[1];
    const float* emb  = (const float*)d_in[2];
    const float* ls   = (const float*)d_in[3];

    const int B = in_sizes[0] / LSEQ;   // 64

    char* ws = (char*)d_ws;
    float2*   params = (float2*)ws;                   // 256 KB
    _Float16* baset  = (_Float16*)(ws + (1u << 18));  // 16 MB

    precompute_all<<<B * NT, 256, 0, stream>>>(bs, ls, emb, params, baset);
    field_mfma<<<B * (PDIM / BM), 256, 0, stream>>>(cpos, params, baset, (float*)d_out);
}

// Round 9
// 76.296 us; speedup vs baseline: 1.0689x; 1.0689x over previous
//
#include <hip/hip_runtime.h>
#include <math.h>

#define LSEQ 512
#define EDIM 256
#define PDIM 2048
#define BM   128
#define BK   32
#define NT   16      // K-steps = LSEQ/BK

typedef _Float16 f16x8  __attribute__((ext_vector_type(8)));
typedef _Float16 f16x2  __attribute__((ext_vector_type(2)));
typedef float    f32x16 __attribute__((ext_vector_type(16)));

#if __has_builtin(__builtin_amdgcn_exp2f)
#define EXP2F(x) __builtin_amdgcn_exp2f(x)
#else
#define EXP2F(x) __expf((x) * 0.6931471805599453f)
#endif

__device__ inline f16x2 pk2(float a, float b) {
#if __has_builtin(__builtin_amdgcn_cvt_pkrtz)
    return __builtin_bit_cast(f16x2, __builtin_amdgcn_cvt_pkrtz(a, b));
#else
    f16x2 r; r[0] = (_Float16)a; r[1] = (_Float16)b; return r;
#endif
}

__device__ inline float hw_sin(float ang) {
#if __has_builtin(__builtin_amdgcn_sinf)
    float rev = ang * 0.15915494309189535f;
    return __builtin_amdgcn_sinf(rev - floorf(rev));
#else
    return sinf(ang);
#endif
}
__device__ inline float hw_cos(float ang) {
#if __has_builtin(__builtin_amdgcn_cosf)
    float rev = ang * 0.15915494309189535f;
    return __builtin_amdgcn_cosf(rev - floorf(rev));
#else
    return cosf(ang);
#endif
}

// Conflict-balanced interleaved tile layout (fp16 element offset) for a
// [rows][32] fp16 tile stored as 128B row-pairs. r = row, g = k-group (0..3).
// Any 32-consecutive-row x fixed-g b128 access spreads 8 words/bank.
__device__ __host__ inline int tile_off(int r, int g) {
    return ((r >> 1) << 6) + ((r & 1) << 5) + (((g ^ ((r >> 1) & 3)) & 3) << 3);
}

__device__ inline void g2lds16(const void* g, void* l) {
    __builtin_amdgcn_global_load_lds(
        (const __attribute__((address_space(1))) void*)g,
        (__attribute__((address_space(3))) void*)l, 16, 0, 0);
}

// ---- fused precompute: one block per (b, k-step) baset chunk ---------------
// Also writes params[b, l] = {-0.5/w^2 * log2e, log2(amp)} for its 32 l's.
__global__ __launch_bounds__(256) void precompute_all(
    const int*   __restrict__ bs,      // (B, L)
    const float* __restrict__ ls,      // (256, 3)
    const float* __restrict__ emb,     // (256, E)
    float2*      __restrict__ params,  // (B, L)
    _Float16*    __restrict__ baset) { // (B*NT) chunks of 16 KB
    const int b   = blockIdx.x >> 4;
    const int t   = blockIdx.x & 15;
    const int tid = threadIdx.x;       // = e (0..255)

    __shared__ int sByte[BK];
    if (tid < BK) {
        const int l    = t * BK + tid;
        const int byte = bs[b * LSEQ + l];
        sByte[tid] = byte;
        const float l1  = ls[byte * 3 + 1];
        const float l2  = ls[byte * 3 + 2];
        const float wdt = fabsf(l1) * 0.02f + 1e-5f;
        const float amp = 1.0f / (1.0f + __expf(-l2));
        params[b * LSEQ + l] = make_float2(-0.72134752f / (wdt * wdt),  // -0.5*log2e/w^2
                                           __log2f(amp));
    }
    __syncthreads();

    // PE dim e: pair index e>>1, phase e&1 (0=sin, 1=cos)
    const float div = __expf((float)(tid >> 1) * (-2.0f * 9.210340372f / 256.0f));
    _Float16* chunk = baset + ((size_t)blockIdx.x << 13);
#pragma unroll
    for (int g = 0; g < 4; ++g) {
        f16x8 v;
#pragma unroll
        for (int j = 0; j < 8; ++j) {
            const int lj  = g * 8 + j;
            const float ang = (float)(t * BK + lj) * div;
            const float pev = (tid & 1) ? hw_cos(ang) : hw_sin(ang);
            v[j] = (_Float16)(emb[sByte[lj] * EDIM + tid] + pev);
        }
        *(f16x8*)&chunk[tile_off(tid, g)] = v;
    }
}

// ----------------------------- MFMA field kernel ----------------------------
// 512 thr (8 waves, 2x4). Tile 128p x 256e, wave tile 64p x 64e, BK=32,
// 16 K-steps, 2-phase dbuf, 32x32x16 f16 MFMA. Params from global (L1),
// genW after the MFMA cluster (decoupled from its lgkm waits).
__global__ __launch_bounds__(512, 4) void field_mfma(
    const float*    __restrict__ cpos,    // (B,P)
    const float2*   __restrict__ params,  // (B,L) {c2*log2e, log2(amp)}
    const _Float16* __restrict__ baset,   // pre-swizzled BASE^T chunks
    float*          __restrict__ out) {   // (B,P,E)

    __shared__ __align__(16) _Float16 sW[2][BM * BK];    // 2 x 8 KB
    __shared__ __align__(16) _Float16 sB[2][EDIM * BK];  // 2 x 16 KB

    const int orig = blockIdx.x;
    const int wg   = (orig & 7) * 128 + (orig >> 3);     // bijective XCD swizzle
    const int b    = wg >> 4;
    const int pt   = wg & 15;

    const int tid = threadIdx.x, lane = tid & 63, wave = tid >> 6;
    const int l31 = lane & 31, h = lane >> 5;            // 32x32 frag lane map
    const int wrow = wave >> 2, wcol = wave & 3;         // 2 x 4 wave grid

    // W-gen role: thread -> (p row sp, k-group sg of 8 l's)
    const int sp = tid >> 2;
    const int sg = tid & 3;
    const float mypos = cpos[b * PDIM + pt * BM + sp];
    const float invL  = 1.0f / (float)(LSEQ - 1);
    const int   woff  = tile_off(sp, sg);

    // frag read offsets: A row = wrow*64 + rt*32 + l31 (rt via +1024),
    //                    B row = wcol*64 + ct*32 + l31
    int aoff[2], boff[2];
#pragma unroll
    for (int kk = 0; kk < 2; ++kk) {
        aoff[kk] = tile_off(wrow * 64 + l31, kk * 2 + h);
        boff[kk] = tile_off(wcol * 64 + l31, kk * 2 + h);
    }

    const float2* prm = params + b * LSEQ;
    const _Float16* bt = baset + ((size_t)b * NT << 13);

    // ---- prologue: stage B0,B1; params(0); genW(0) ----
#pragma unroll
    for (int buf = 0; buf < 2; ++buf) {
        const _Float16* src = bt + buf * 8192 + wave * 1024 + lane * 8;
        g2lds16(src,       &sB[buf][wave * 1024]);
        g2lds16(src + 512, &sB[buf][wave * 1024 + 512]);
    }

    float4 q0, q1, q2, q3;
    {
        const float4* qp = (const float4*)(prm + sg * 8);
        q0 = qp[0]; q1 = qp[1]; q2 = qp[2]; q3 = qp[3];
    }

    // genW for K-step t into sW[dbuf] using q0..q3 (= params for this t)
    auto genW = [&](int t, int dbuf) {
        const float bl0 = (float)(t * BK + sg * 8) * invL;
        const float pd  = mypos - bl0;
        float w[8];
#define GW(i, c2, la) { float d = pd - (float)(i) * invL; \
                        w[i] = EXP2F(fmaf(d * d, (c2), (la))); }
        GW(0, q0.x, q0.y) GW(1, q0.z, q0.w)
        GW(2, q1.x, q1.y) GW(3, q1.z, q1.w)
        GW(4, q2.x, q2.y) GW(5, q2.z, q2.w)
        GW(6, q3.x, q3.y) GW(7, q3.z, q3.w)
#undef GW
        f16x8 wv;
        ((f16x2*)&wv)[0] = pk2(w[0], w[1]);
        ((f16x2*)&wv)[1] = pk2(w[2], w[3]);
        ((f16x2*)&wv)[2] = pk2(w[4], w[5]);
        ((f16x2*)&wv)[3] = pk2(w[6], w[7]);
        *(f16x8*)&sW[dbuf][woff] = wv;
    };

    genW(0, 0);
    __syncthreads();

    f32x16 acc[2][2];
#pragma unroll
    for (int i = 0; i < 2; ++i)
#pragma unroll
        for (int j = 0; j < 2; ++j) acc[i][j] = (f32x16)(0.f);

    // ---- main loop: one barrier per K-step ----
    for (int t = 0; t < NT; ++t) {
        const int cur = t & 1;

        if (t < NT - 1) {   // issue params(t+1); consumed after MFMA cluster
            const float4* qp = (const float4*)(prm + (t + 1) * BK + sg * 8);
            q0 = qp[0]; q1 = qp[1]; q2 = qp[2]; q3 = qp[3];
        }

        const _Float16* wb_ = sW[cur];
        const _Float16* bb_ = sB[cur];
        __builtin_amdgcn_s_setprio(1);
#pragma unroll
        for (int kk = 0; kk < 2; ++kk) {
            f16x8 fa[2], fb[2];
#pragma unroll
            for (int rt = 0; rt < 2; ++rt) fa[rt] = *(const f16x8*)&wb_[aoff[kk] + rt * 1024];
#pragma unroll
            for (int ct = 0; ct < 2; ++ct) fb[ct] = *(const f16x8*)&bb_[boff[kk] + ct * 1024];
#pragma unroll
            for (int ct = 0; ct < 2; ++ct)
#pragma unroll
                for (int rt = 0; rt < 2; ++rt)
                    acc[rt][ct] = __builtin_amdgcn_mfma_f32_32x32x16_f16(fa[rt], fb[ct], acc[rt][ct], 0, 0, 0);
        }
        __builtin_amdgcn_s_setprio(0);

        if (t < NT - 1) genW(t + 1, cur ^ 1);  // after MFMA: no lgkm coupling

        __syncthreads();   // drains W[t+1] ds_writes + B[t+1] stage gloads

        if (t < NT - 2) {  // issue B[t+2] into the buffer just freed
            const _Float16* src = bt + (t + 2) * 8192 + wave * 1024 + lane * 8;
            g2lds16(src,       &sB[cur][wave * 1024]);
            g2lds16(src + 512, &sB[cur][wave * 1024 + 512]);
        }
    }

    // ---- epilogue: C/D 32x32 layout col=lane&31, row=(reg&3)+8(reg>>2)+4h --
#pragma unroll
    for (int rt = 0; rt < 2; ++rt)
#pragma unroll
        for (int ct = 0; ct < 2; ++ct) {
            const int e = wcol * 64 + ct * 32 + l31;
            const int pbase = pt * BM + wrow * 64 + rt * 32 + 4 * h;
#pragma unroll
            for (int reg = 0; reg < 16; ++reg) {
                const int p = pbase + (reg & 3) + 8 * (reg >> 2);
                out[((size_t)b * PDIM + p) * EDIM + e] = acc[rt][ct][reg];
            }
        }
}

extern "C" void kernel_launch(void* const* d_in, const int* in_sizes, int n_in,
                              void* d_out, int out_size, void* d_ws, size_t ws_size,
                              hipStream_t stream) {
    const int*   bs   = (const int*)d_in[0];
    const float* cpos = (const float*)d_in[1];
    const float* emb  = (const float*)d_in[2];
    const float* ls   = (const float*)d_in[3];

    const int B = in_sizes[0] / LSEQ;   // 64

    char* ws = (char*)d_ws;
    float2*   params = (float2*)ws;                   // 256 KB
    _Float16* baset  = (_Float16*)(ws + (1u << 18));  // 16 MB

    precompute_all<<<B * NT, 256, 0, stream>>>(bs, ls, emb, params, baset);
    field_mfma<<<B * (PDIM / BM), 512, 0, stream>>>(cpos, params, baset, (float*)d_out);
}